// Round 3
// 542.423 us; speedup vs baseline: 2.4166x; 2.4166x over previous
//
#include <hip/hip_runtime.h>
#include <hip/hip_bf16.h>

// db4 synthesis filters. g1[j] = (-1)^j * g0[7-j].
__device__ constexpr float G0[8] = {
    0.23037781330885523f,  0.7148465705525415f,  0.6308807679295904f,  -0.02798376941698385f,
    -0.18703481171888114f, 0.030841381835986965f, 0.032883011666982945f, -0.010597401784997278f};
__device__ constexpr float G1[8] = {
    -0.010597401784997278f, -0.032883011666982945f, 0.030841381835986965f, 0.18703481171888114f,
    -0.02798376941698385f,  -0.6308807679295904f,   0.7148465705525415f,  -0.23037781330885523f};

// One level of 3D inverse db4 DWT as a direct gather (tensor-product expansion).
// low:(16,n,n,n) highs:(16,7,n,n,n) -> out:(16,N,N,N), N=2n-6.
//
// out[gz][gy][gx] = sum_{band} sum_{mz,my,mx in 0..3}
//     src_band[(gz>>1)+3-mz][(gy>>1)+3-my][(gx>>1)+3-mx]
//     * Wz[(gz&1)+2mz] * Wy[(gy&1)+2my] * Wx[(gx&1)+2mx]
// where W* = G1 if the band's bit for that axis is set else G0 (bit0=x,bit1=y,bit2=z).
// Indices provably in-bounds: u+3-m in [u, u+3], max = (N/2-1)+3 = n-1.
//
// R0 change (L2-BW theory): each thread computes the FULL 2x2x2 parity block
// (outputs 2u+{0,1} on all three axes). All 8 outputs share the exact same
// 8 bands x 16 rows x 4 floats of source -> L2 read traffic per output drops
// 4x vs the x-pair version (2048B per 8B out -> 2048B per 32B out), and the
// x-dots d0/d1 amortize over the 4 zy-parities.
__global__ __launch_bounds__(256) void idwt3_gather8(const float* __restrict__ low,
                                                     const float* __restrict__ highs,
                                                     float* __restrict__ out,
                                                     int n, int N) {
  const int b = blockIdx.y;
  const long n3 = (long)n * n * n;
  const int H = N >> 1;                 // output 2x2x2-blocks per axis
  const int nthreads = H * H * H;
  const int q = blockIdx.x * 256 + threadIdx.x;
  if (q >= nthreads) return;
  const int ux = q % H;
  const int t1 = q / H;
  const int uy = t1 % H;
  const int uz = t1 / H;

  const int nn = n * n;
  // Base offset of the (mz=0,my=0) row; row (mz,my) is at  base - mz*nn - my*n.
  const long o00 = ((long)(uz + 3) * n + (uy + 3)) * n + ux;

  float acc[2][2][2] = {};  // [pz][py][px]

#pragma unroll
  for (int band = 0; band < 8; ++band) {
    const float* src = (band == 0) ? (low + (long)b * n3)
                                   : (highs + ((long)b * 7 + (band - 1)) * n3);
    const int sx = band & 1, sy = (band >> 1) & 1, sz = band >> 2;
    const float* Gx = sx ? G1 : G0;   // folds at compile time (band unrolled)
    const float* Gy = sy ? G1 : G0;
    const float* Gz = sz ? G1 : G0;
    const float* sb = src + o00;
#pragma unroll
    for (int mz = 0; mz < 4; ++mz) {
      const float wz0 = Gz[2 * mz];      // pz = 0
      const float wz1 = Gz[2 * mz + 1];  // pz = 1
#pragma unroll
      for (int my = 0; my < 4; ++my) {
        const float* row = sb - mz * nn - my * n;
        const float r0 = row[0], r1 = row[1], r2 = row[2], r3 = row[3];
        // x-dot: input idx ux+3-mx pairs with Wx[px+2mx] -> row[3-mx] * Gx[px+2mx]
        const float d0 = r3 * Gx[0] + r2 * Gx[2] + r1 * Gx[4] + r0 * Gx[6];
        const float d1 = r3 * Gx[1] + r2 * Gx[3] + r1 * Gx[5] + r0 * Gx[7];
        const float wy0 = Gy[2 * my];
        const float wy1 = Gy[2 * my + 1];
        const float c00 = wz0 * wy0;  // constants after unroll
        const float c01 = wz0 * wy1;
        const float c10 = wz1 * wy0;
        const float c11 = wz1 * wy1;
        acc[0][0][0] = fmaf(d0, c00, acc[0][0][0]);
        acc[0][0][1] = fmaf(d1, c00, acc[0][0][1]);
        acc[0][1][0] = fmaf(d0, c01, acc[0][1][0]);
        acc[0][1][1] = fmaf(d1, c01, acc[0][1][1]);
        acc[1][0][0] = fmaf(d0, c10, acc[1][0][0]);
        acc[1][0][1] = fmaf(d1, c10, acc[1][0][1]);
        acc[1][1][0] = fmaf(d0, c11, acc[1][1][0]);
        acc[1][1][1] = fmaf(d1, c11, acc[1][1][1]);
      }
    }
  }

  const long N3 = (long)N * N * N;
  float* o = out + (long)b * N3 + ((long)(2 * uz) * N + (2 * uy)) * N + (2 * ux);
#pragma unroll
  for (int pz = 0; pz < 2; ++pz) {
#pragma unroll
    for (int py = 0; py < 2; ++py) {
      // 2*ux is even -> 8B-aligned float2 store.
      float2 v = make_float2(acc[pz][py][0], acc[pz][py][1]);
      *reinterpret_cast<float2*>(o + (long)pz * N * N + (long)py * N) = v;
    }
  }
}

extern "C" void kernel_launch(void* const* d_in, const int* in_sizes, int n_in,
                              void* d_out, int out_size, void* d_ws, size_t ws_size,
                              hipStream_t stream) {
  // Identify inputs BY SIZE (element counts — confirmed R5 of prior session):
  //   yl  (2,8,36^3)    =   746,496
  //   yh0 (2,8,7,66^3)  = 32,199,552
  //   yh1 (2,8,7,36^3)  =  5,225,472
  const float* yl  = nullptr;
  const float* yh0 = nullptr;
  const float* yh1 = nullptr;
  for (int i = 0; i < n_in; ++i) {
    if (in_sizes[i] == 746496)        yl  = (const float*)d_in[i];
    else if (in_sizes[i] == 32199552) yh0 = (const float*)d_in[i];
    else if (in_sizes[i] == 5225472)  yh1 = (const float*)d_in[i];
  }
  if (!yl || !yh0 || !yh1) {
    yl  = (const float*)d_in[0];
    yh0 = (const float*)d_in[1];
    yh1 = (const float*)d_in[2];
  }
  float* out = (float*)d_out;      // fp32 output (verified prior session)
  float* ll  = (float*)d_ws;       // (16,66^3) fp32 = 18.4 MB inter-level buffer

  // Level 1: (36 -> 66), highs = yh1. 33^3 = 35937 threads/volume -> 141 blocks.
  idwt3_gather8<<<dim3(141, 16), 256, 0, stream>>>(yl, yh1, ll, 36, 66);

  // Level 2: (66 -> 126), highs = yh0. 63^3 = 250047 threads/volume -> 977 blocks.
  idwt3_gather8<<<dim3(977, 16), 256, 0, stream>>>(ll, yh0, out, 66, 126);
}